// Round 7
// baseline (1363.252 us; speedup 1.0000x reference)
//
#include <hip/hip_runtime.h>

typedef unsigned short u16;
typedef __attribute__((ext_vector_type(8))) short bf16x8;   // 8 bf16 (4 VGPRs)
typedef __attribute__((ext_vector_type(4))) float f32x4;

#define D_EMB 1024
#define NBAT  256
#define AS1 __attribute__((address_space(1)))
#define AS3 __attribute__((address_space(3)))
// Compiler-only memory barrier: pins LDS ds_write/ds_read program order
// (HW executes a wave's DS ops in order; TBAA would otherwise allow
// reordering across differently-typed LDS accesses -- the R6 bug).
#define MEMBAR() asm volatile("" ::: "memory")

__device__ __forceinline__ u16 f2bf(float f){
    unsigned int u = __float_as_uint(f);
    unsigned int r = (u + 0x7fffu + ((u >> 16) & 1u)) >> 16;  // RNE
    return (u16)r;
}
__device__ __forceinline__ float leaky(float x){ return x > 0.f ? x : 0.1f * x; }

// bf16-pair helpers (truncation pack; unpack = 1 VALU inst)
__device__ __forceinline__ unsigned pack2(float a, float b){
    return (__float_as_uint(a) >> 16) | (__float_as_uint(b) & 0xffff0000u);
}
__device__ __forceinline__ float unpk_lo(unsigned p){ return __uint_as_float(p << 16); }
__device__ __forceinline__ float unpk_hi(unsigned p){ return __uint_as_float(p & 0xffff0000u); }

// ---------------------------------------------------------------------------
// Pack img_emb(+pool_img as row 36) and cap_emb(+pool_txt as row 40) to bf16.
// ---------------------------------------------------------------------------
__global__ void pack_kernel(const float* __restrict__ pool_img, const float* __restrict__ img_emb,
                            const float* __restrict__ pool_txt, const float* __restrict__ cap_emb,
                            u16* __restrict__ imgw, u16* __restrict__ capw){
    int row = blockIdx.x;            // 0..19967
    const float* src; u16* dst;
    if (row < NBAT * 37){
        int e = row / 37, rr = row - e * 37;
        src = (rr < 36) ? (img_emb + ((size_t)e * 36 + rr) * D_EMB) : (pool_img + (size_t)e * D_EMB);
        dst = imgw + (size_t)row * D_EMB;
    } else {
        int r2 = row - NBAT * 37;
        int e = r2 / 41, rr = r2 - e * 41;
        src = (rr < 40) ? (cap_emb + ((size_t)e * 40 + rr) * D_EMB) : (pool_txt + (size_t)e * D_EMB);
        dst = capw + (size_t)r2 * D_EMB;
    }
    int t = threadIdx.x;
    float4 v = ((const float4*)src)[t];
    unsigned long long pk = (unsigned long long)f2bf(v.x)
        | ((unsigned long long)f2bf(v.y) << 16)
        | ((unsigned long long)f2bf(v.z) << 32)
        | ((unsigned long long)f2bf(v.w) << 48);
    *(unsigned long long*)(dst + (size_t)t * 4) = pk;
}

// ---------------------------------------------------------------------------
// Pool-vector norms
// ---------------------------------------------------------------------------
__global__ void norm_kernel(const float* __restrict__ pool_img, const float* __restrict__ pool_txt,
                            float* __restrict__ w1i, float* __restrict__ w1t){
    __shared__ float red[256];
    int v = blockIdx.x;
    const float* src = (v < 256) ? (pool_img + (size_t)v * D_EMB)
                                 : (pool_txt + (size_t)(v - 256) * D_EMB);
    int t = threadIdx.x;
    float4 x = ((const float4*)src)[t];
    red[t] = x.x*x.x + x.y*x.y + x.z*x.z + x.w*x.w;
    __syncthreads();
    for (int off = 128; off > 0; off >>= 1){
        if (t < off) red[t] += red[t + off];
        __syncthreads();
    }
    if (t == 0){
        float n = sqrtf(red[0]);
        if (v < 256) w1i[v] = n; else w1t[v - 256] = n;
    }
}

// ---------------------------------------------------------------------------
// MFMA Gram kernel -> bf16 zero-padded [48][64] output (A-frag friendly).
// blk<256 -> G[b] (R=36), else H[b] (R=40). Pads (row>=R || col>=R) are ZERO:
// they kill all garbage terms in the fused kernel's zz-MFMA (A-side zeros).
// ---------------------------------------------------------------------------
__launch_bounds__(256, 2)
__global__ void gram_kernel(const u16* __restrict__ imgw, const u16* __restrict__ capw,
                            u16* __restrict__ Gp, u16* __restrict__ Hp){
    __shared__ __align__(16) char gsm[6144];
    int blk = blockIdx.x;
    int tid = threadIdx.x, lane = tid & 63;
    int wave = __builtin_amdgcn_readfirstlane(tid >> 6);
    int frow = lane & 15, q = lane >> 4;

    const u16* E; u16* Gout; int R;
    if (blk < NBAT){ E = imgw + (size_t)blk * 37 * D_EMB; Gout = Gp + (size_t)blk * 3072; R = 36; }
    else { int b = blk - NBAT; E = capw + (size_t)b * 41 * D_EMB; Gout = Hp + (size_t)b * 3072; R = 40; }

    // zero the pad region (disjoint from valid writes below -> no race)
    for (int idx = tid; idx < 3072; idx += 256){
        int row = idx >> 6, col = idx & 63;
        if (row >= R || col >= R) Gout[idx] = 0;
    }

    {   uint4 z = {0u,0u,0u,0u};
        for (int off = tid * 16; off < 6144; off += 4096) *(uint4*)(gsm + off) = z;
    }

    const u16* gsrc[2]; int goff[2]; bool gval[2];
    #pragma unroll
    for (int j = 0; j < 2; ++j){
        int g = wave + j * 4;
        gval[j] = false; gsrc[j] = E; goff[j] = 0;
        if (g < 6){
            int kk = g / 3, t = g - kk * 3;
            int row = t * 16 + frow;
            gsrc[j] = E + (size_t)row * D_EMB + kk * 32 + q * 8;
            goff[j] = g * 1024;
            gval[j] = (row < R);
        }
    }

    int wm = wave >> 1, wn = wave & 1;
    int nTm = wm ? 1 : 2, nTn = wn ? 1 : 2;
    f32x4 acc[2][2];
    #pragma unroll
    for (int a = 0; a < 2; ++a)
        #pragma unroll
        for (int b = 0; b < 2; ++b) acc[a][b] = (f32x4){0.f,0.f,0.f,0.f};

    for (int c = 0; c < 16; ++c){
        __syncthreads();
        #pragma unroll
        for (int j = 0; j < 2; ++j){
            if (gval[j]){
                __builtin_amdgcn_global_load_lds(
                    (const AS1 void*)(const void*)(gsrc[j] + c * 64),
                    (AS3 void*)(void*)(gsm + goff[j] + lane * 16),
                    16, 0, 0);
            }
        }
        __syncthreads();
        #pragma unroll
        for (int kk = 0; kk < 2; ++kk){
            bf16x8 fA[2], fB[2];
            #pragma unroll
            for (int mi = 0; mi < 2; ++mi)
                if (mi < nTm) fA[mi] = *(const bf16x8*)(gsm + ((kk * 3 + (wm + mi * 2)) * 64 + lane) * 16);
            #pragma unroll
            for (int ni = 0; ni < 2; ++ni)
                if (ni < nTn) fB[ni] = *(const bf16x8*)(gsm + ((kk * 3 + (wn + ni * 2)) * 64 + lane) * 16);
            #pragma unroll
            for (int mi = 0; mi < 2; ++mi)
                if (mi < nTm)
                    #pragma unroll
                    for (int ni = 0; ni < 2; ++ni)
                        if (ni < nTn)
                            acc[mi][ni] = __builtin_amdgcn_mfma_f32_16x16x32_bf16(
                                fA[mi], fB[ni], acc[mi][ni], 0, 0, 0);
        }
    }

    #pragma unroll
    for (int mi = 0; mi < 2; ++mi){
        if (mi < nTm){
            int tm = wm + mi * 2;
            #pragma unroll
            for (int ni = 0; ni < 2; ++ni){
                if (ni < nTn){
                    int tn = wn + ni * 2;
                    int col = tn * 16 + frow;
                    if (col < R){
                        #pragma unroll
                        for (int g = 0; g < 4; ++g){
                            int row = tm * 16 + q * 4 + g;
                            if (row < R) Gout[row * 64 + col] = f2bf(acc[mi][ni][g]);
                        }
                    }
                }
            }
        }
    }
}

// ---------------------------------------------------------------------------
// Fused main kernel. One block = 2 images x 2 captions.
// LDS layout (32768 B exactly -> 5 blocks/CU at bounds (256,5)):
//   [0,24568)      Call [74][83] f32 (staging [0,22528) overlaid pre-epilogue)
//   [24576,32768)  per-pair zz buffer: 4 waves x 2048 B (two 1 KB frag slots),
//                  zeroed once; untouched parts stay zero (kill k-pad terms).
// zz = diag(U^T G U) via MFMA: A = bf16 padded Gram (global, L2-resident),
// B = softmax weights written to the pair slot in frag order; diag extracted
// with one ds_read per tile. All post-phase LDS comm is wave-internal (per-
// wave DS ops are in-order); MEMBAR() pins compiler order across the
// mixed-type LDS accesses (the R6 TBAA-reordering bug).
// ---------------------------------------------------------------------------
__launch_bounds__(256, 5)
__global__ void fused_kernel(const u16* __restrict__ imgw, const u16* __restrict__ capw,
                             const u16* __restrict__ Gp, const u16* __restrict__ Hp,
                             const float* __restrict__ w1i, const float* __restrict__ w1t,
                             float* __restrict__ out){
    __shared__ __align__(16) char smem[32768];
    float* Call = (float*)smem;                 // [74][83] overlay after GEMM

    int tid  = threadIdx.x;
    int lane = tid & 63;
    int wave = __builtin_amdgcn_readfirstlane(tid >> 6);
    int frow = lane & 15, q = lane >> 4;

    int lin = blockIdx.x;
    int xcd = lin & 7;                   // XCD-ownership swizzle (R5: 14x fetch cut)
    int s   = lin >> 3;
    int b_t = (xcd << 4) | (s & 15);
    int i_t = s >> 4;
    int b0 = b_t * 2, i0 = i_t * 2;
    const u16* Ag = imgw + (size_t)b0 * 37 * D_EMB;
    const u16* Bg = capw + (size_t)i0 * 41 * D_EMB;

    {   // zero staging pad slots + the whole zz buffer (one-time)
        uint4 z = {0u,0u,0u,0u};
        for (int off = tid * 16; off < 22528; off += 4096) *(uint4*)(smem + off) = z;
        *(uint4*)(smem + 24576 + tid * 32)      = z;
        *(uint4*)(smem + 24576 + tid * 32 + 16) = z;
    }

    const u16* gsrc[6]; int goff[6]; bool gval[6];
    #pragma unroll
    for (int j = 0; j < 6; ++j){
        int g = wave + j * 4;
        gval[j] = false; gsrc[j] = Ag; goff[j] = 0;
        if (g < 22){
            if (g < 10){
                int tm = g % 5, kk = g / 5;
                int row = tm * 16 + frow;
                gsrc[j] = Ag + (size_t)row * D_EMB + kk * 32 + q * 8;
                goff[j] = g * 1024;
                gval[j] = (row < 74);
            } else {
                int gb = g - 10;
                int tn = gb % 6, kk = gb / 6;
                int row = tn * 16 + frow;
                gsrc[j] = Bg + (size_t)row * D_EMB + kk * 32 + q * 8;
                goff[j] = 10240 + gb * 1024;
                gval[j] = (row < 82);
            }
        }
    }

    int wm = wave >> 1, wn = wave & 1;
    int nTm = wm ? 2 : 3;
    f32x4 acc[3][3];
    #pragma unroll
    for (int aa = 0; aa < 3; ++aa)
        #pragma unroll
        for (int bb = 0; bb < 3; ++bb) acc[aa][bb] = (f32x4){0.f, 0.f, 0.f, 0.f};

    for (int c = 0; c < 16; ++c){
        __syncthreads();
        #pragma unroll
        for (int j = 0; j < 6; ++j){
            if (gval[j]){
                __builtin_amdgcn_global_load_lds(
                    (const AS1 void*)(const void*)(gsrc[j] + c * 64),
                    (AS3 void*)(void*)(smem + goff[j] + lane * 16),
                    16, 0, 0);
            }
        }
        __syncthreads();
        #pragma unroll
        for (int kk = 0; kk < 2; ++kk){
            bf16x8 bfr[3];
            #pragma unroll
            for (int ni = 0; ni < 3; ++ni){
                int tn = wn + ni * 2;
                bfr[ni] = *(const bf16x8*)(smem + 10240 + ((kk * 6 + tn) * 64 + lane) * 16);
            }
            #pragma unroll
            for (int mi = 0; mi < 3; ++mi){
                if (mi < nTm){
                    int tm = wm + mi * 2;
                    bf16x8 af = *(const bf16x8*)(smem + ((kk * 5 + tm) * 64 + lane) * 16);
                    #pragma unroll
                    for (int ni = 0; ni < 3; ++ni){
                        acc[mi][ni] = __builtin_amdgcn_mfma_f32_16x16x32_bf16(
                            af, bfr[ni], acc[mi][ni], 0, 0, 0);
                    }
                }
            }
        }
    }
    __syncthreads();

    // C/D layout: col = lane&15 (B-row), row = (lane>>4)*4 + reg (A-row)
    #pragma unroll
    for (int mi = 0; mi < 3; ++mi){
        if (mi < nTm){
            int tm = wm + mi * 2;
            #pragma unroll
            for (int ni = 0; ni < 3; ++ni){
                int tn = wn + ni * 2;
                int col = tn * 16 + frow;
                int rbase = tm * 16 + q * 4;
                if (col < 82){
                    #pragma unroll
                    for (int g = 0; g < 4; ++g){
                        int rowc = rbase + g;
                        if (rowc < 74) Call[rowc * 83 + col] = acc[mi][ni][g];
                    }
                }
            }
        }
    }
    __syncthreads();

    // ----- post-processing: one wave per (b,i) pair -----
    int pb = wave >> 1, pi = wave & 1;
    int bg = b0 + pb, ig = i0 + pi;
    const float* Sv = Call + (pb * 37) * 83 + pi * 41;  // S[r*83+l]; p[r]=S[r*83+40]; qv[l]=S[36*83+l]
    const u16* Gb = Gp + (size_t)bg * 3072;             // bf16 [48][64]
    const u16* Hb = Hp + (size_t)ig * 3072;
    char*  pbuf  = smem + 24576 + wave * 2048;          // [kc0 1KB][kc1 1KB]
    float* pnorm = (float*)pbuf;                        // transient (clobbered by slots)

    float t2i_sum, i2t_sum;

    // ======== t2i ========
    {   // row norms (lanes = regions)
        int r0 = (lane < 36) ? lane : 35;
        float s2 = 0.f;
        #pragma unroll
        for (int l = 0; l < 40; ++l){ float x = leaky(Sv[r0 * 83 + l]); s2 = fmaf(x, x, s2); }
        if (lane < 36) pnorm[lane] = 1.f / (sqrtf(s2) + 1e-8f);
        MEMBAR();
    }
    {   // exp weights (lanes = words), packed bf16 pairs
        int lc = (lane < 40) ? lane : 39;
        unsigned up[18];
        float num = 0.f;
        #pragma unroll
        for (int r = 0; r < 36; r += 2){
            float x0 = leaky(Sv[r * 83 + lc]);
            float e0 = __expf(9.0f * x0 * pnorm[r]);
            float x1 = leaky(Sv[(r + 1) * 83 + lc]);
            float e1 = __expf(9.0f * x1 * pnorm[r + 1]);
            num = fmaf(e0, Sv[r * 83 + 40], fmaf(e1, Sv[(r + 1) * 83 + 40], num));
            up[r >> 1] = pack2(e0, e1);
        }
        MEMBAR();   // all pnorm reads complete before B-writes clobber pbuf
        // zz = diag(U^T G U) via MFMA
        float zzp[3];
        #pragma unroll
        for (int ni = 0; ni < 3; ++ni){
            if (lane < 40 && (lane >> 4) == ni){
                int fr = lane & 15;
                #pragma unroll
                for (int qq = 0; qq < 4; ++qq){
                    uint4 w = {up[qq * 4], up[qq * 4 + 1], up[qq * 4 + 2], up[qq * 4 + 3]};
                    *(uint4*)(pbuf + (qq * 16 + fr) * 16) = w;           // kc0
                }
                uint4 w1 = {up[16], up[17], 0u, 0u};                     // k 32..39 (r36..39 = 0)
                *(uint4*)(pbuf + 1024 + fr * 16) = w1;                   // kc1 q'=0
            }
            MEMBAR();   // writes before fragment/diag reads
            uint4 tb0 = *(const uint4*)(pbuf + lane * 16);
            uint4 tb1 = *(const uint4*)(pbuf + 1024 + lane * 16);
            bf16x8 B0 = __builtin_bit_cast(bf16x8, tb0);
            bf16x8 B1 = __builtin_bit_cast(bf16x8, tb1);
            float zp = 0.f;
            #pragma unroll
            for (int mi = 0; mi < 3; ++mi){
                bf16x8 A0 = *(const bf16x8*)(Gb + (mi * 16 + frow) * 64 + q * 8);
                bf16x8 A1 = *(const bf16x8*)(Gb + (mi * 16 + frow) * 64 + 32 + q * 8);
                f32x4 w = (f32x4){0.f, 0.f, 0.f, 0.f};
                w = __builtin_amdgcn_mfma_f32_16x16x32_bf16(A0, B0, w, 0, 0, 0);
                w = __builtin_amdgcn_mfma_f32_16x16x32_bf16(A1, B1, w, 0, 0, 0);
                int k0 = mi * 16 + q * 4;
                int kc = k0 >> 5, km = k0 & 31;
                uint2 ud = *(const uint2*)(pbuf + kc * 1024 + ((km >> 3) * 16 + frow) * 16 + (q & 1) * 8);
                zp = fmaf(w[0], unpk_lo(ud.x), zp);
                zp = fmaf(w[1], unpk_hi(ud.x), zp);
                zp = fmaf(w[2], unpk_lo(ud.y), zp);
                zp = fmaf(w[3], unpk_hi(ud.y), zp);
            }
            zzp[ni] = zp;
            MEMBAR();   // reads complete before next iteration's writes
        }
        #pragma unroll
        for (int ni = 0; ni < 3; ++ni){
            zzp[ni] += __shfl_xor(zzp[ni], 16);
            zzp[ni] += __shfl_xor(zzp[ni], 32);
        }
        int sel = lc >> 4;
        float zz = (sel == 0) ? zzp[0] : ((sel == 1) ? zzp[1] : zzp[2]);
        float sim = num / fmaxf(w1t[ig] * sqrtf(fmaxf(zz, 0.f)), 1e-8f);
        sim = (lane < 40) ? sim : 0.f;
        #pragma unroll
        for (int off = 32; off > 0; off >>= 1) sim += __shfl_down(sim, off);
        t2i_sum = sim;
    }

    // ======== i2t ========
    MEMBAR();
    {   // column norms (lanes = words)
        int l0 = (lane < 40) ? lane : 39;
        float s2 = 0.f;
        #pragma unroll
        for (int r = 0; r < 36; ++r){ float x = leaky(Sv[r * 83 + l0]); s2 = fmaf(x, x, s2); }
        if (lane < 40) pnorm[lane] = 1.f / (sqrtf(s2) + 1e-8f);
        MEMBAR();
    }
    {   // exp weights (lanes = regions)
        int rc = (lane < 36) ? lane : 35;
        unsigned vp[20];
        float num = 0.f;
        #pragma unroll
        for (int l = 0; l < 40; l += 2){
            float x0 = leaky(Sv[rc * 83 + l]);
            float e0 = __expf(9.0f * x0 * pnorm[l]);
            float x1 = leaky(Sv[rc * 83 + l + 1]);
            float e1 = __expf(9.0f * x1 * pnorm[l + 1]);
            num = fmaf(e0, Sv[36 * 83 + l], fmaf(e1, Sv[36 * 83 + l + 1], num));
            vp[l >> 1] = pack2(e0, e1);
        }
        MEMBAR();
        float zzp[3];
        #pragma unroll
        for (int ni = 0; ni < 3; ++ni){
            if (lane < 36 && (lane >> 4) == ni){
                int fr = lane & 15;
                #pragma unroll
                for (int qq = 0; qq < 4; ++qq){
                    uint4 w = {vp[qq * 4], vp[qq * 4 + 1], vp[qq * 4 + 2], vp[qq * 4 + 3]};
                    *(uint4*)(pbuf + (qq * 16 + fr) * 16) = w;           // kc0
                }
                uint4 w1 = {vp[16], vp[17], vp[18], vp[19]};             // k 32..39
                *(uint4*)(pbuf + 1024 + fr * 16) = w1;                   // kc1 q'=0
            }
            MEMBAR();
            uint4 tb0 = *(const uint4*)(pbuf + lane * 16);
            uint4 tb1 = *(const uint4*)(pbuf + 1024 + lane * 16);
            bf16x8 B0 = __builtin_bit_cast(bf16x8, tb0);
            bf16x8 B1 = __builtin_bit_cast(bf16x8, tb1);
            float zp = 0.f;
            #pragma unroll
            for (int mi = 0; mi < 3; ++mi){
                bf16x8 A0 = *(const bf16x8*)(Hb + (mi * 16 + frow) * 64 + q * 8);
                bf16x8 A1 = *(const bf16x8*)(Hb + (mi * 16 + frow) * 64 + 32 + q * 8);
                f32x4 w = (f32x4){0.f, 0.f, 0.f, 0.f};
                w = __builtin_amdgcn_mfma_f32_16x16x32_bf16(A0, B0, w, 0, 0, 0);
                w = __builtin_amdgcn_mfma_f32_16x16x32_bf16(A1, B1, w, 0, 0, 0);
                int k0 = mi * 16 + q * 4;
                int kc = k0 >> 5, km = k0 & 31;
                uint2 ud = *(const uint2*)(pbuf + kc * 1024 + ((km >> 3) * 16 + frow) * 16 + (q & 1) * 8);
                zp = fmaf(w[0], unpk_lo(ud.x), zp);
                zp = fmaf(w[1], unpk_hi(ud.x), zp);
                zp = fmaf(w[2], unpk_lo(ud.y), zp);
                zp = fmaf(w[3], unpk_hi(ud.y), zp);
            }
            zzp[ni] = zp;
            MEMBAR();
        }
        #pragma unroll
        for (int ni = 0; ni < 3; ++ni){
            zzp[ni] += __shfl_xor(zzp[ni], 16);
            zzp[ni] += __shfl_xor(zzp[ni], 32);
        }
        int sel = rc >> 4;
        float zz = (sel == 0) ? zzp[0] : ((sel == 1) ? zzp[1] : zzp[2]);
        float sim = num / fmaxf(w1i[bg] * sqrtf(fmaxf(zz, 0.f)), 1e-8f);
        sim = (lane < 36) ? sim : 0.f;
        #pragma unroll
        for (int off = 32; off > 0; off >>= 1) sim += __shfl_down(sim, off);
        i2t_sum = sim;
    }

    if (lane == 0)
        out[bg * 256 + ig] = t2i_sum * (1.f / 40.f) + i2t_sum * (1.f / 36.f) + Sv[36 * 83 + 40];
}

// ---------------------------------------------------------------------------
extern "C" void kernel_launch(void* const* d_in, const int* in_sizes, int n_in,
                              void* d_out, int out_size, void* d_ws, size_t ws_size,
                              hipStream_t stream){
    const float* pool_img = (const float*)d_in[0];
    const float* img_emb  = (const float*)d_in[1];
    const float* pool_txt = (const float*)d_in[2];
    const float* cap_emb  = (const float*)d_in[3];
    float* out = (float*)d_out;

    char* ws = (char*)d_ws;                         // needs ~44.1 MB
    size_t o = 0;
    u16* imgw = (u16*)(ws + o);  o += (size_t)256 * 37 * 1024 * 2;   // 19,398,656
    u16* capw = (u16*)(ws + o);  o += (size_t)256 * 41 * 1024 * 2;   // 21,495,808
    u16* Gp   = (u16*)(ws + o);  o += (size_t)256 * 48 * 64 * 2;     //  1,572,864
    u16* Hp   = (u16*)(ws + o);  o += (size_t)256 * 48 * 64 * 2;     //  1,572,864
    float* w1i = (float*)(ws + o); o += 1024;
    float* w1t = (float*)(ws + o); o += 1024;

    pack_kernel<<<19968, 256, 0, stream>>>(pool_img, img_emb, pool_txt, cap_emb, imgw, capw);
    norm_kernel<<<512, 256, 0, stream>>>(pool_img, pool_txt, w1i, w1t);
    gram_kernel<<<512, 256, 0, stream>>>(imgw, capw, Gp, Hp);
    fused_kernel<<<16384, 256, 0, stream>>>(imgw, capw, Gp, Hp, w1i, w1t, out);
}

// Round 8
// 944.595 us; speedup vs baseline: 1.4432x; 1.4432x over previous
//
#include <hip/hip_runtime.h>

typedef unsigned short u16;
typedef __attribute__((ext_vector_type(8))) short bf16x8;   // 8 bf16 (4 VGPRs)
typedef __attribute__((ext_vector_type(4))) float f32x4;

#define D_EMB 1024
#define NBAT  256
#define AS1 __attribute__((address_space(1)))
#define AS3 __attribute__((address_space(3)))
// Compiler-only memory barrier: pins LDS ds_write/ds_read program order
// (HW executes a wave's DS ops in order; validated functionally in R7).
#define MEMBAR() asm volatile("" ::: "memory")

__device__ __forceinline__ u16 f2bf(float f){
    unsigned int u = __float_as_uint(f);
    unsigned int r = (u + 0x7fffu + ((u >> 16) & 1u)) >> 16;  // RNE
    return (u16)r;
}
__device__ __forceinline__ float leaky(float x){ return x > 0.f ? x : 0.1f * x; }

// bf16-pair helpers (truncation pack; unpack = 1 VALU inst)
__device__ __forceinline__ unsigned pack2(float a, float b){
    return (__float_as_uint(a) >> 16) | (__float_as_uint(b) & 0xffff0000u);
}
__device__ __forceinline__ float unpk_lo(unsigned p){ return __uint_as_float(p << 16); }
__device__ __forceinline__ float unpk_hi(unsigned p){ return __uint_as_float(p & 0xffff0000u); }

// ---------------------------------------------------------------------------
// Pack img_emb(+pool_img as row 36) and cap_emb(+pool_txt as row 40) to bf16.
// ---------------------------------------------------------------------------
__global__ void pack_kernel(const float* __restrict__ pool_img, const float* __restrict__ img_emb,
                            const float* __restrict__ pool_txt, const float* __restrict__ cap_emb,
                            u16* __restrict__ imgw, u16* __restrict__ capw){
    int row = blockIdx.x;            // 0..19967
    const float* src; u16* dst;
    if (row < NBAT * 37){
        int e = row / 37, rr = row - e * 37;
        src = (rr < 36) ? (img_emb + ((size_t)e * 36 + rr) * D_EMB) : (pool_img + (size_t)e * D_EMB);
        dst = imgw + (size_t)row * D_EMB;
    } else {
        int r2 = row - NBAT * 37;
        int e = r2 / 41, rr = r2 - e * 41;
        src = (rr < 40) ? (cap_emb + ((size_t)e * 40 + rr) * D_EMB) : (pool_txt + (size_t)e * D_EMB);
        dst = capw + (size_t)r2 * D_EMB;
    }
    int t = threadIdx.x;
    float4 v = ((const float4*)src)[t];
    unsigned long long pk = (unsigned long long)f2bf(v.x)
        | ((unsigned long long)f2bf(v.y) << 16)
        | ((unsigned long long)f2bf(v.z) << 32)
        | ((unsigned long long)f2bf(v.w) << 48);
    *(unsigned long long*)(dst + (size_t)t * 4) = pk;
}

// ---------------------------------------------------------------------------
// Pool-vector norms
// ---------------------------------------------------------------------------
__global__ void norm_kernel(const float* __restrict__ pool_img, const float* __restrict__ pool_txt,
                            float* __restrict__ w1i, float* __restrict__ w1t){
    __shared__ float red[256];
    int v = blockIdx.x;
    const float* src = (v < 256) ? (pool_img + (size_t)v * D_EMB)
                                 : (pool_txt + (size_t)(v - 256) * D_EMB);
    int t = threadIdx.x;
    float4 x = ((const float4*)src)[t];
    red[t] = x.x*x.x + x.y*x.y + x.z*x.z + x.w*x.w;
    __syncthreads();
    for (int off = 128; off > 0; off >>= 1){
        if (t < off) red[t] += red[t + off];
        __syncthreads();
    }
    if (t == 0){
        float n = sqrtf(red[0]);
        if (v < 256) w1i[v] = n; else w1t[v - 256] = n;
    }
}

// ---------------------------------------------------------------------------
// MFMA Gram kernel -> bf16 zero-padded [48][64] output (A-frag friendly).
// blk<256 -> G[b] (R=36), else H[b] (R=40). Pads (row>=R || col>=R) are ZERO.
// ---------------------------------------------------------------------------
__launch_bounds__(256, 2)
__global__ void gram_kernel(const u16* __restrict__ imgw, const u16* __restrict__ capw,
                            u16* __restrict__ Gp, u16* __restrict__ Hp){
    __shared__ __align__(16) char gsm[6144];
    int blk = blockIdx.x;
    int tid = threadIdx.x, lane = tid & 63;
    int wave = __builtin_amdgcn_readfirstlane(tid >> 6);
    int frow = lane & 15, q = lane >> 4;

    const u16* E; u16* Gout; int R;
    if (blk < NBAT){ E = imgw + (size_t)blk * 37 * D_EMB; Gout = Gp + (size_t)blk * 3072; R = 36; }
    else { int b = blk - NBAT; E = capw + (size_t)b * 41 * D_EMB; Gout = Hp + (size_t)b * 3072; R = 40; }

    for (int idx = tid; idx < 3072; idx += 256){
        int row = idx >> 6, col = idx & 63;
        if (row >= R || col >= R) Gout[idx] = 0;
    }

    {   uint4 z = {0u,0u,0u,0u};
        for (int off = tid * 16; off < 6144; off += 4096) *(uint4*)(gsm + off) = z;
    }

    const u16* gsrc[2]; int goff[2]; bool gval[2];
    #pragma unroll
    for (int j = 0; j < 2; ++j){
        int g = wave + j * 4;
        gval[j] = false; gsrc[j] = E; goff[j] = 0;
        if (g < 6){
            int kk = g / 3, t = g - kk * 3;
            int row = t * 16 + frow;
            gsrc[j] = E + (size_t)row * D_EMB + kk * 32 + q * 8;
            goff[j] = g * 1024;
            gval[j] = (row < R);
        }
    }

    int wm = wave >> 1, wn = wave & 1;
    int nTm = wm ? 1 : 2, nTn = wn ? 1 : 2;
    f32x4 acc[2][2];
    #pragma unroll
    for (int a = 0; a < 2; ++a)
        #pragma unroll
        for (int b = 0; b < 2; ++b) acc[a][b] = (f32x4){0.f,0.f,0.f,0.f};

    for (int c = 0; c < 16; ++c){
        __syncthreads();
        #pragma unroll
        for (int j = 0; j < 2; ++j){
            if (gval[j]){
                __builtin_amdgcn_global_load_lds(
                    (const AS1 void*)(const void*)(gsrc[j] + c * 64),
                    (AS3 void*)(void*)(gsm + goff[j] + lane * 16),
                    16, 0, 0);
            }
        }
        __syncthreads();
        #pragma unroll
        for (int kk = 0; kk < 2; ++kk){
            bf16x8 fA[2], fB[2];
            #pragma unroll
            for (int mi = 0; mi < 2; ++mi)
                if (mi < nTm) fA[mi] = *(const bf16x8*)(gsm + ((kk * 3 + (wm + mi * 2)) * 64 + lane) * 16);
            #pragma unroll
            for (int ni = 0; ni < 2; ++ni)
                if (ni < nTn) fB[ni] = *(const bf16x8*)(gsm + ((kk * 3 + (wn + ni * 2)) * 64 + lane) * 16);
            #pragma unroll
            for (int mi = 0; mi < 2; ++mi)
                if (mi < nTm)
                    #pragma unroll
                    for (int ni = 0; ni < 2; ++ni)
                        if (ni < nTn)
                            acc[mi][ni] = __builtin_amdgcn_mfma_f32_16x16x32_bf16(
                                fA[mi], fB[ni], acc[mi][ni], 0, 0, 0);
        }
    }

    #pragma unroll
    for (int mi = 0; mi < 2; ++mi){
        if (mi < nTm){
            int tm = wm + mi * 2;
            #pragma unroll
            for (int ni = 0; ni < 2; ++ni){
                if (ni < nTn){
                    int tn = wn + ni * 2;
                    int col = tn * 16 + frow;
                    if (col < R){
                        #pragma unroll
                        for (int g = 0; g < 4; ++g){
                            int row = tm * 16 + q * 4 + g;
                            if (row < R) Gout[row * 64 + col] = f2bf(acc[mi][ni][g]);
                        }
                    }
                }
            }
        }
    }
}

// ---------------------------------------------------------------------------
// Fused main kernel. One block = 2 images x 2 captions.
// LDS (31744 B <= 32K -> 5 blocks/CU at bounds (256,5)):
//   [0,24568)       Call [74][83] f32 (staging [0,22528) overlaid pre-epilogue)
//   [24576,31744)   4 wave slots x 1792 B: kc0 diag copy [0,1024),
//                   kc1 row0 [1024,1280) (row1 [1280,1536) stays init-zero),
//                   pnorm [1536,1696)
// zz = diag(U^T G U) via MFMA with B-fragments built JUST-IN-TIME in frag
// layout (lane (q,n') computes e[k=q*8+j][n']) -> no persistent weight
// arrays -> no scratch spill (the R7 failure). LDS copy only for the diag
// read; num via per-lane partials + shfl_xor(16/32).
// ---------------------------------------------------------------------------
__launch_bounds__(256, 5)
__global__ void fused_kernel(const u16* __restrict__ imgw, const u16* __restrict__ capw,
                             const u16* __restrict__ Gp, const u16* __restrict__ Hp,
                             const float* __restrict__ w1i, const float* __restrict__ w1t,
                             float* __restrict__ out){
    __shared__ __align__(16) char smem[32768];
    float* Call = (float*)smem;                 // [74][83] overlay after GEMM

    int tid  = threadIdx.x;
    int lane = tid & 63;
    int wave = __builtin_amdgcn_readfirstlane(tid >> 6);
    int frow = lane & 15, q = lane >> 4;

    int lin = blockIdx.x;
    int xcd = lin & 7;                   // XCD-ownership swizzle (R5: 14x fetch cut)
    int s   = lin >> 3;
    int b_t = (xcd << 4) | (s & 15);
    int i_t = s >> 4;
    int b0 = b_t * 2, i0 = i_t * 2;
    const u16* Ag = imgw + (size_t)b0 * 37 * D_EMB;
    const u16* Bg = capw + (size_t)i0 * 41 * D_EMB;

    {   // zero staging pad slots + entire post region (kc1 row1 must stay 0)
        uint4 z = {0u,0u,0u,0u};
        for (int off = tid * 16; off < 22528; off += 4096) *(uint4*)(smem + off) = z;
        *(uint4*)(smem + 24576 + tid * 32)      = z;
        *(uint4*)(smem + 24576 + tid * 32 + 16) = z;
    }

    const u16* gsrc[6]; int goff[6]; bool gval[6];
    #pragma unroll
    for (int j = 0; j < 6; ++j){
        int g = wave + j * 4;
        gval[j] = false; gsrc[j] = Ag; goff[j] = 0;
        if (g < 22){
            if (g < 10){
                int tm = g % 5, kk = g / 5;
                int row = tm * 16 + frow;
                gsrc[j] = Ag + (size_t)row * D_EMB + kk * 32 + q * 8;
                goff[j] = g * 1024;
                gval[j] = (row < 74);
            } else {
                int gb = g - 10;
                int tn = gb % 6, kk = gb / 6;
                int row = tn * 16 + frow;
                gsrc[j] = Bg + (size_t)row * D_EMB + kk * 32 + q * 8;
                goff[j] = 10240 + gb * 1024;
                gval[j] = (row < 82);
            }
        }
    }

    int wm = wave >> 1, wn = wave & 1;
    int nTm = wm ? 2 : 3;
    f32x4 acc[3][3];
    #pragma unroll
    for (int aa = 0; aa < 3; ++aa)
        #pragma unroll
        for (int bb = 0; bb < 3; ++bb) acc[aa][bb] = (f32x4){0.f, 0.f, 0.f, 0.f};

    for (int c = 0; c < 16; ++c){
        __syncthreads();
        #pragma unroll
        for (int j = 0; j < 6; ++j){
            if (gval[j]){
                __builtin_amdgcn_global_load_lds(
                    (const AS1 void*)(const void*)(gsrc[j] + c * 64),
                    (AS3 void*)(void*)(smem + goff[j] + lane * 16),
                    16, 0, 0);
            }
        }
        __syncthreads();
        #pragma unroll
        for (int kk = 0; kk < 2; ++kk){
            bf16x8 bfr[3];
            #pragma unroll
            for (int ni = 0; ni < 3; ++ni){
                int tn = wn + ni * 2;
                bfr[ni] = *(const bf16x8*)(smem + 10240 + ((kk * 6 + tn) * 64 + lane) * 16);
            }
            #pragma unroll
            for (int mi = 0; mi < 3; ++mi){
                if (mi < nTm){
                    int tm = wm + mi * 2;
                    bf16x8 af = *(const bf16x8*)(smem + ((kk * 5 + tm) * 64 + lane) * 16);
                    #pragma unroll
                    for (int ni = 0; ni < 3; ++ni){
                        acc[mi][ni] = __builtin_amdgcn_mfma_f32_16x16x32_bf16(
                            af, bfr[ni], acc[mi][ni], 0, 0, 0);
                    }
                }
            }
        }
    }
    __syncthreads();

    // C/D layout: col = lane&15 (B-row), row = (lane>>4)*4 + reg (A-row)
    #pragma unroll
    for (int mi = 0; mi < 3; ++mi){
        if (mi < nTm){
            int tm = wm + mi * 2;
            #pragma unroll
            for (int ni = 0; ni < 3; ++ni){
                int tn = wn + ni * 2;
                int col = tn * 16 + frow;
                int rbase = tm * 16 + q * 4;
                if (col < 82){
                    #pragma unroll
                    for (int g = 0; g < 4; ++g){
                        int rowc = rbase + g;
                        if (rowc < 74) Call[rowc * 83 + col] = acc[mi][ni][g];
                    }
                }
            }
        }
    }
    __syncthreads();

    // ----- post-processing: one wave per (b,i) pair -----
    int pb = wave >> 1, pi = wave & 1;
    int bg = b0 + pb, ig = i0 + pi;
    const float* Sv = Call + (pb * 37) * 83 + pi * 41;  // S[r*83+l]; p[r]=S[r*83+40]; qv[l]=S[36*83+l]
    const u16* Gb = Gp + (size_t)bg * 3072;             // bf16 [48][64]
    const u16* Hb = Hp + (size_t)ig * 3072;
    char*  slot = smem + 24576 + wave * 1792;           // kc0 | kc1 | pnorm
    float* pn   = (float*)(slot + 1536);
    bool   c1   = (lane < 16);                          // q==0 group

    float t2i_sum, i2t_sum;

    // ======== t2i:  zz[word] = u^T G u,  num[word] = u . p ========
    {   // row norms over words (lanes = regions)
        int r0 = (lane < 36) ? lane : 35;
        float s2 = 0.f;
        #pragma unroll
        for (int l = 0; l < 40; ++l){ float x = leaky(Sv[r0 * 83 + l]); s2 = fmaf(x, x, s2); }
        if (lane < 36) pn[lane] = 1.f / (sqrtf(s2) + 1e-8f);
        MEMBAR();
    }
    {
        float zzp[3], nmp[3];
        #pragma unroll
        for (int ni = 0; ni < 3; ++ni){
            int wcol = ni * 16 + frow;               // word (>=40 garbage cols unused)
            unsigned bv0[4]; float nump = 0.f;
            #pragma unroll
            for (int d = 0; d < 4; ++d){             // k = q*8 + 2d, 2d+1  (r < 32)
                int r = q * 8 + 2 * d;
                float e0 = __expf(fminf(9.f * leaky(Sv[r * 83 + wcol]) * pn[r], 30.f));
                float e1 = __expf(fminf(9.f * leaky(Sv[(r + 1) * 83 + wcol]) * pn[r + 1], 30.f));
                nump = fmaf(e0, Sv[r * 83 + 40], fmaf(e1, Sv[(r + 1) * 83 + 40], nump));
                bv0[d] = pack2(e0, e1);
            }
            unsigned bv1[4] = {0u, 0u, 0u, 0u};      // k 32..39; r 36..39 are zero pad
            #pragma unroll
            for (int d = 0; d < 2; ++d){             // r = 32..35
                int r = 32 + 2 * d;
                float e0 = __expf(fminf(9.f * leaky(Sv[r * 83 + wcol]) * pn[r], 30.f));
                float e1 = __expf(fminf(9.f * leaky(Sv[(r + 1) * 83 + wcol]) * pn[r + 1], 30.f));
                e0 = c1 ? e0 : 0.f;  e1 = c1 ? e1 : 0.f;
                nump = fmaf(e0, Sv[r * 83 + 40], fmaf(e1, Sv[(r + 1) * 83 + 40], nump));
                bv1[d] = pack2(e0, e1);
            }
            uint4 t0 = {bv0[0], bv0[1], bv0[2], bv0[3]};
            uint4 t1 = {bv1[0], bv1[1], bv1[2], bv1[3]};
            *(uint4*)(slot + lane * 16) = t0;                     // kc0 diag copy
            if (lane < 16) *(uint4*)(slot + 1024 + frow * 16) = t1;  // kc1 row0
            MEMBAR();
            bf16x8 B0 = __builtin_bit_cast(bf16x8, t0);
            bf16x8 B1 = __builtin_bit_cast(bf16x8, t1);
            float zp = 0.f;
            #pragma unroll
            for (int mi = 0; mi < 3; ++mi){
                bf16x8 A0 = *(const bf16x8*)(Gb + (mi * 16 + frow) * 64 + q * 8);
                bf16x8 A1 = *(const bf16x8*)(Gb + (mi * 16 + frow) * 64 + 32 + q * 8);
                f32x4 w = (f32x4){0.f, 0.f, 0.f, 0.f};
                w = __builtin_amdgcn_mfma_f32_16x16x32_bf16(A0, B0, w, 0, 0, 0);
                w = __builtin_amdgcn_mfma_f32_16x16x32_bf16(A1, B1, w, 0, 0, 0);
                int m0 = mi * 16 + q * 4, kc = m0 >> 5, km = m0 & 31;
                uint2 ud = *(const uint2*)(slot + kc * 1024 + ((km >> 3) * 16 + frow) * 16 + (q & 1) * 8);
                zp = fmaf(w[0], unpk_lo(ud.x), zp);
                zp = fmaf(w[1], unpk_hi(ud.x), zp);
                zp = fmaf(w[2], unpk_lo(ud.y), zp);
                zp = fmaf(w[3], unpk_hi(ud.y), zp);
            }
            MEMBAR();
            zp   += __shfl_xor(zp, 16);   zp   += __shfl_xor(zp, 32);
            nump += __shfl_xor(nump, 16); nump += __shfl_xor(nump, 32);
            zzp[ni] = zp;  nmp[ni] = nump;
        }
        int lc = (lane < 40) ? lane : 39;
        int sel = lc >> 4;
        float zz  = (sel == 0) ? zzp[0] : ((sel == 1) ? zzp[1] : zzp[2]);
        float num = (sel == 0) ? nmp[0] : ((sel == 1) ? nmp[1] : nmp[2]);
        float sim = num / fmaxf(w1t[ig] * sqrtf(fmaxf(zz, 0.f)), 1e-8f);
        sim = (lane < 40) ? sim : 0.f;
        #pragma unroll
        for (int off = 32; off > 0; off >>= 1) sim += __shfl_down(sim, off);
        t2i_sum = sim;
    }

    // ======== i2t:  zz[region] = v^T H v,  num[region] = v . qv ========
    MEMBAR();
    {   // column norms over regions (lanes = words)
        int l0 = (lane < 40) ? lane : 39;
        float s2 = 0.f;
        #pragma unroll
        for (int r = 0; r < 36; ++r){ float x = leaky(Sv[r * 83 + l0]); s2 = fmaf(x, x, s2); }
        if (lane < 40) pn[lane] = 1.f / (sqrtf(s2) + 1e-8f);
        MEMBAR();
    }
    {
        float zzp[3], nmp[3];
        #pragma unroll
        for (int ni = 0; ni < 3; ++ni){
            int rr = ni * 16 + frow;                 // region (>=36 garbage cols unused)
            unsigned bv0[4]; float nump = 0.f;
            #pragma unroll
            for (int d = 0; d < 4; ++d){             // k = l = q*8 + 2d, 2d+1  (< 32)
                int l = q * 8 + 2 * d;
                float e0 = __expf(fminf(9.f * leaky(Sv[rr * 83 + l]) * pn[l], 30.f));
                float e1 = __expf(fminf(9.f * leaky(Sv[rr * 83 + l + 1]) * pn[l + 1], 30.f));
                nump = fmaf(e0, Sv[36 * 83 + l], fmaf(e1, Sv[36 * 83 + l + 1], nump));
                bv0[d] = pack2(e0, e1);
            }
            unsigned bv1[4];                          // k = l = 32..39 (all valid)
            #pragma unroll
            for (int d = 0; d < 4; ++d){
                int l = 32 + 2 * d;
                float e0 = __expf(fminf(9.f * leaky(Sv[rr * 83 + l]) * pn[l], 30.f));
                float e1 = __expf(fminf(9.f * leaky(Sv[rr * 83 + l + 1]) * pn[l + 1], 30.f));
                e0 = c1 ? e0 : 0.f;  e1 = c1 ? e1 : 0.f;
                nump = fmaf(e0, Sv[36 * 83 + l], fmaf(e1, Sv[36 * 83 + l + 1], nump));
                bv1[d] = pack2(e0, e1);
            }
            uint4 t0 = {bv0[0], bv0[1], bv0[2], bv0[3]};
            uint4 t1 = {bv1[0], bv1[1], bv1[2], bv1[3]};
            *(uint4*)(slot + lane * 16) = t0;
            if (lane < 16) *(uint4*)(slot + 1024 + frow * 16) = t1;
            MEMBAR();
            bf16x8 B0 = __builtin_bit_cast(bf16x8, t0);
            bf16x8 B1 = __builtin_bit_cast(bf16x8, t1);
            float zp = 0.f;
            #pragma unroll
            for (int mi = 0; mi < 3; ++mi){
                bf16x8 A0 = *(const bf16x8*)(Hb + (mi * 16 + frow) * 64 + q * 8);
                bf16x8 A1 = *(const bf16x8*)(Hb + (mi * 16 + frow) * 64 + 32 + q * 8);
                f32x4 w = (f32x4){0.f, 0.f, 0.f, 0.f};
                w = __builtin_amdgcn_mfma_f32_16x16x32_bf16(A0, B0, w, 0, 0, 0);
                w = __builtin_amdgcn_mfma_f32_16x16x32_bf16(A1, B1, w, 0, 0, 0);
                int m0 = mi * 16 + q * 4, kc = m0 >> 5, km = m0 & 31;
                uint2 ud = *(const uint2*)(slot + kc * 1024 + ((km >> 3) * 16 + frow) * 16 + (q & 1) * 8);
                zp = fmaf(w[0], unpk_lo(ud.x), zp);
                zp = fmaf(w[1], unpk_hi(ud.x), zp);
                zp = fmaf(w[2], unpk_lo(ud.y), zp);
                zp = fmaf(w[3], unpk_hi(ud.y), zp);
            }
            MEMBAR();
            zp   += __shfl_xor(zp, 16);   zp   += __shfl_xor(zp, 32);
            nump += __shfl_xor(nump, 16); nump += __shfl_xor(nump, 32);
            zzp[ni] = zp;  nmp[ni] = nump;
        }
        int rc = (lane < 36) ? lane : 35;
        int sel = rc >> 4;
        float zz  = (sel == 0) ? zzp[0] : ((sel == 1) ? zzp[1] : zzp[2]);
        float num = (sel == 0) ? nmp[0] : ((sel == 1) ? nmp[1] : nmp[2]);
        float sim = num / fmaxf(w1i[bg] * sqrtf(fmaxf(zz, 0.f)), 1e-8f);
        sim = (lane < 36) ? sim : 0.f;
        #pragma unroll
        for (int off = 32; off > 0; off >>= 1) sim += __shfl_down(sim, off);
        i2t_sum = sim;
    }

    if (lane == 0)
        out[bg * 256 + ig] = t2i_sum * (1.f / 40.f) + i2t_sum * (1.f / 36.f) + Sv[36 * 83 + 40];
}

// ---------------------------------------------------------------------------
extern "C" void kernel_launch(void* const* d_in, const int* in_sizes, int n_in,
                              void* d_out, int out_size, void* d_ws, size_t ws_size,
                              hipStream_t stream){
    const float* pool_img = (const float*)d_in[0];
    const float* img_emb  = (const float*)d_in[1];
    const float* pool_txt = (const float*)d_in[2];
    const float* cap_emb  = (const float*)d_in[3];
    float* out = (float*)d_out;

    char* ws = (char*)d_ws;                         // needs ~44.1 MB
    size_t o = 0;
    u16* imgw = (u16*)(ws + o);  o += (size_t)256 * 37 * 1024 * 2;   // 19,398,656
    u16* capw = (u16*)(ws + o);  o += (size_t)256 * 41 * 1024 * 2;   // 21,495,808
    u16* Gp   = (u16*)(ws + o);  o += (size_t)256 * 48 * 64 * 2;     //  1,572,864
    u16* Hp   = (u16*)(ws + o);  o += (size_t)256 * 48 * 64 * 2;     //  1,572,864
    float* w1i = (float*)(ws + o); o += 1024;
    float* w1t = (float*)(ws + o); o += 1024;

    pack_kernel<<<19968, 256, 0, stream>>>(pool_img, img_emb, pool_txt, cap_emb, imgw, capw);
    norm_kernel<<<512, 256, 0, stream>>>(pool_img, pool_txt, w1i, w1t);
    gram_kernel<<<512, 256, 0, stream>>>(imgw, capw, Gp, Hp);
    fused_kernel<<<16384, 256, 0, stream>>>(imgw, capw, Gp, Hp, w1i, w1t, out);
}